// Round 12
// baseline (174.693 us; speedup 1.0000x reference)
//
#include <hip/hip_runtime.h>
#include <math.h>

#define HH 56
#define WW 56
#define CC 256
#define TT 8
#define HW 3136

// ---------------- K1: attn conv2d, shuffle-taps + 4ch groups + prefetch ---
// grid = bt(32) x rowband(14 of 4 rows) x csplit(4 of 64ch) = 1792 blocks.
// Wave owns one output row; lane = column. Per 4-channel group: 12 coalesced
// row loads (prefetched ONE GROUP AHEAD into regs), horizontal taps via
// __shfl_up/down (DPP), 144 FMAs. No LDS, no barriers. Weights wave-uniform
// -> scalar loads. Fixes round-11's barrier/vmcnt stalls (VALUBusy 28%).
__global__ __launch_bounds__(256)
void k1_attn(const float* __restrict__ x, const float* __restrict__ aw,
             float* __restrict__ attn_raw) {
    const int blk  = blockIdx.x;
    const int cs   = blk & 3;
    const int ht   = (blk >> 2) % 14;
    const int bt   = blk / 56;
    const int wave = threadIdx.x >> 6;
    const int lane = threadIdx.x & 63;
    const int row  = ht * 4 + wave;
    const int col  = lane;
    const bool live = col < WW;
    const bool okm = row > 0, okp = row < HH - 1;
    const int base = row * WW + col;
    const int offm = okm ? base - WW : base;     // clamped (safe) addresses
    const int offp = okp ? base + WW : base;
    const float* xb = x + ((size_t)bt * CC + cs * 64) * HW;

    float acc0 = 0.f, acc1 = 0.f, acc2 = 0.f, acc3 = 0.f;

    // prologue: load channel group 0
    float cm[4], cc[4], cp[4];
    #pragma unroll
    for (int j = 0; j < 4; ++j) {
        const float* xp = xb + (size_t)j * HW;
        cm[j] = (live && okm) ? xp[offm] : 0.f;
        cc[j] = live ? xp[base] : 0.f;
        cp[j] = (live && okp) ? xp[offp] : 0.f;
    }

    for (int it = 0; it < 16; ++it) {
        // prefetch next group's 12 values (consumed AFTER this group's compute)
        float nm[4], nc[4], np[4];
        if (it < 15) {
            #pragma unroll
            for (int j = 0; j < 4; ++j) {
                const float* xp = xb + (size_t)(it * 4 + 4 + j) * HW;
                nm[j] = (live && okm) ? xp[offm] : 0.f;
                nc[j] = live ? xp[base] : 0.f;
                np[j] = (live && okp) ? xp[offp] : 0.f;
            }
        }
        const int c0 = cs * 64 + it * 4;
        #pragma unroll
        for (int j = 0; j < 4; ++j) {
            float vm = cm[j], vc = cc[j], vp = cp[j];
            // horizontal neighbors via cross-lane shuffle
            float vml = __shfl_up(vm, 1), vcl = __shfl_up(vc, 1), vpl = __shfl_up(vp, 1);
            if (lane == 0) { vml = 0.f; vcl = 0.f; vpl = 0.f; }
            float vmr = __shfl_down(vm, 1), vcr = __shfl_down(vc, 1), vpr = __shfl_down(vp, 1);
            // lanes >=56 hold 0 -> right edge (col 55) pulls 0 naturally

            const int c = c0 + j;
            const float* w0 = aw + ((size_t)0 * CC + c) * 9;   // uniform -> s_load
            const float* w1 = aw + ((size_t)1 * CC + c) * 9;
            const float* w2 = aw + ((size_t)2 * CC + c) * 9;
            const float* w3 = aw + ((size_t)3 * CC + c) * 9;

            acc0 = fmaf(w0[0], vml, acc0); acc0 = fmaf(w0[1], vm, acc0); acc0 = fmaf(w0[2], vmr, acc0);
            acc0 = fmaf(w0[3], vcl, acc0); acc0 = fmaf(w0[4], vc, acc0); acc0 = fmaf(w0[5], vcr, acc0);
            acc0 = fmaf(w0[6], vpl, acc0); acc0 = fmaf(w0[7], vp, acc0); acc0 = fmaf(w0[8], vpr, acc0);

            acc1 = fmaf(w1[0], vml, acc1); acc1 = fmaf(w1[1], vm, acc1); acc1 = fmaf(w1[2], vmr, acc1);
            acc1 = fmaf(w1[3], vcl, acc1); acc1 = fmaf(w1[4], vc, acc1); acc1 = fmaf(w1[5], vcr, acc1);
            acc1 = fmaf(w1[6], vpl, acc1); acc1 = fmaf(w1[7], vp, acc1); acc1 = fmaf(w1[8], vpr, acc1);

            acc2 = fmaf(w2[0], vml, acc2); acc2 = fmaf(w2[1], vm, acc2); acc2 = fmaf(w2[2], vmr, acc2);
            acc2 = fmaf(w2[3], vcl, acc2); acc2 = fmaf(w2[4], vc, acc2); acc2 = fmaf(w2[5], vcr, acc2);
            acc2 = fmaf(w2[6], vpl, acc2); acc2 = fmaf(w2[7], vp, acc2); acc2 = fmaf(w2[8], vpr, acc2);

            acc3 = fmaf(w3[0], vml, acc3); acc3 = fmaf(w3[1], vm, acc3); acc3 = fmaf(w3[2], vmr, acc3);
            acc3 = fmaf(w3[3], vcl, acc3); acc3 = fmaf(w3[4], vc, acc3); acc3 = fmaf(w3[5], vcr, acc3);
            acc3 = fmaf(w3[6], vpl, acc3); acc3 = fmaf(w3[7], vp, acc3); acc3 = fmaf(w3[8], vpr, acc3);
        }
        // rotate prefetched group into current
        if (it < 15) {
            #pragma unroll
            for (int j = 0; j < 4; ++j) { cm[j] = nm[j]; cc[j] = nc[j]; cp[j] = np[j]; }
        }
    }
    if (live) {
        atomicAdd(&attn_raw[((size_t)bt * 4 + 0) * HW + base], acc0);
        atomicAdd(&attn_raw[((size_t)bt * 4 + 1) * HW + base], acc1);
        atomicAdd(&attn_raw[((size_t)bt * 4 + 2) * HW + base], acc2);
        atomicAdd(&attn_raw[((size_t)bt * 4 + 3) * HW + base], acc3);
    }
}

// ---------------- K1b: attn = sigmoid(relu(raw + bias)) -------------------
__global__ void k1b_act(const float* __restrict__ raw, const float* __restrict__ ab,
                        float* __restrict__ attn) {
    int i = blockIdx.x * 256 + threadIdx.x;
    if (i >= 32 * 4 * HW) return;
    int o = (i / HW) & 3;
    float z = fmaxf(raw[i] + ab[o], 0.f);
    attn[i] = 1.f / (1.f + expf(-z));
}

// ---------------- K2: per-channel BN partial sums of xh = x*attn ----------
__global__ __launch_bounds__(256)
void k2_stats(const float* __restrict__ x, const float* __restrict__ attn,
              float* __restrict__ bn_sum, float* __restrict__ bn_sumsq) {
    const int c  = blockIdx.x & 255;
    const int bt = blockIdx.x >> 8;
    const int head = c >> 6;
    const float4* xp = (const float4*)(x + ((size_t)bt * CC + c) * HW);
    const float4* ap = (const float4*)(attn + ((size_t)bt * 4 + head) * HW);
    float s = 0.f, s2 = 0.f;
    for (int i = threadIdx.x; i < HW / 4; i += 256) {
        float4 xv = xp[i], av = ap[i];
        float v0 = xv.x * av.x, v1 = xv.y * av.y, v2 = xv.z * av.z, v3 = xv.w * av.w;
        s  += v0 + v1 + v2 + v3;
        s2 += v0 * v0 + v1 * v1 + v2 * v2 + v3 * v3;
    }
    #pragma unroll
    for (int off = 32; off > 0; off >>= 1) {
        s  += __shfl_down(s, off);
        s2 += __shfl_down(s2, off);
    }
    __shared__ float red[8];
    const int wave = threadIdx.x >> 6;
    if ((threadIdx.x & 63) == 0) { red[wave * 2] = s; red[wave * 2 + 1] = s2; }
    __syncthreads();
    if (threadIdx.x == 0) {
        atomicAdd(&bn_sum[c],   red[0] + red[2] + red[4] + red[6]);
        atomicAdd(&bn_sumsq[c], red[1] + red[3] + red[5] + red[7]);
    }
}

// ---------------- K3: finalize BN -> per-channel scale/shift --------------
__global__ void k3_final(const float* __restrict__ bn_sum, const float* __restrict__ bn_sumsq,
                         const float* __restrict__ gamma, const float* __restrict__ beta,
                         float* __restrict__ scale, float* __restrict__ shift) {
    int c = threadIdx.x;
    const float invN = 1.f / 100352.f;            // B*T*H*W
    float mean = bn_sum[c] * invN;
    float var  = bn_sumsq[c] * invN - mean * mean;
    float sc   = gamma[c] * rsqrtf(var + 1e-5f);
    scale[c] = sc;
    shift[c] = fmaf(-mean, sc, beta[c]);
}

// ---------------- K4: grouped dilated conv3d, t-vectorized LDS ------------
__global__ __launch_bounds__(256)
void k4_gate(const float* __restrict__ x, const float* __restrict__ attn,
             const float* __restrict__ scale, const float* __restrict__ shift,
             const float* __restrict__ gw0, const float* __restrict__ gw1,
             float* __restrict__ gate_raw) {
    const int blk   = blockIdx.x;
    const int chunk = blk & 31;             // 32 chunks x 8 channels
    const int ht    = (blk >> 5) % 14;
    const int b     = blk / (32 * 14);
    const int h0    = ht * 4;
    const int g     = chunk >> 4;           // group: ch 0..127 -> 0, else 1
    const int head  = chunk >> 3;           // 8-ch chunk sits inside one head
    __shared__ float tile[2][348 * 12];     // 33408 B
    const int tid = threadIdx.x;

    int   pgoff[2];
    bool  pvld[2];
    float pav[2][8];
    #pragma unroll
    for (int k = 0; k < 2; ++k) {
        int p = tid + k * 256;
        bool in = p < 348;
        int r   = p / 58;
        int col = p - r * 58;
        int gh = h0 + r - 1, gw = col - 1;
        bool v = in && (unsigned)gh < HH && (unsigned)gw < WW;
        pvld[k]  = v;
        pgoff[k] = gh * WW + gw;
        #pragma unroll
        for (int t = 0; t < 8; ++t)
            pav[k][t] = v ? attn[((size_t)(b * 8 + t) * 4 + head) * HW + pgoff[k]] : 0.f;
        if (in && !v) {
            float4 z = make_float4(0.f, 0.f, 0.f, 0.f);
            *(float4*)&tile[0][p * 12]     = z;
            *(float4*)&tile[0][p * 12 + 4] = z;
            *(float4*)&tile[1][p * 12]     = z;
            *(float4*)&tile[1][p * 12 + 4] = z;
        }
    }

    {
        const int c0 = chunk * 8;
        const float sc = scale[c0], sh = shift[c0];
        #pragma unroll
        for (int k = 0; k < 2; ++k)
            if (pvld[k]) {
                float v[8];
                #pragma unroll
                for (int t = 0; t < 8; ++t) {
                    float xv = x[((size_t)((b * 8 + t) * CC + c0)) * HW + pgoff[k]];
                    v[t] = fmaxf(fmaf(xv * pav[k][t], sc, sh), 0.f);
                }
                int p = tid + k * 256;
                *(float4*)&tile[0][p * 12]     = make_float4(v[0], v[1], v[2], v[3]);
                *(float4*)&tile[0][p * 12 + 4] = make_float4(v[4], v[5], v[6], v[7]);
            }
    }
    __syncthreads();

    const int wc = tid % WW;
    const int hr = tid / WW;
    const bool active = tid < 4 * WW;
    float acc[2][8];
    #pragma unroll
    for (int d = 0; d < 2; ++d)
        #pragma unroll
        for (int t = 0; t < 8; ++t) acc[d][t] = 0.f;

    for (int cl = 0; cl < 8; ++cl) {
        const int c = chunk * 8 + cl;
        float xn[2][8];
        if (cl < 7) {
            #pragma unroll
            for (int k = 0; k < 2; ++k)
                if (pvld[k]) {
                    #pragma unroll
                    for (int t = 0; t < 8; ++t)
                        xn[k][t] = x[((size_t)((b * 8 + t) * CC + c + 1)) * HW + pgoff[k]];
                }
        }
        if (active) {
            const float* buf = &tile[cl & 1][0];
            const int ci = c & 127;
            const float* wp0 = gw0 + ((size_t)g * 128 + ci) * 27;
            const float* wp1 = gw1 + ((size_t)g * 128 + ci) * 27;
            #pragma unroll
            for (int ki = 0; ki < 3; ++ki) {
                #pragma unroll
                for (int kj = 0; kj < 3; ++kj) {
                    const int tap = ki * 3 + kj;
                    const int pos = (hr + ki) * 58 + wc + kj;
                    const float4 A = *(const float4*)(buf + pos * 12);
                    const float4 B = *(const float4*)(buf + pos * 12 + 4);
                    const float vv[8] = {A.x, A.y, A.z, A.w, B.x, B.y, B.z, B.w};
                    #pragma unroll
                    for (int kd = 0; kd < 3; ++kd) {
                        const float w0 = wp0[kd * 9 + tap];
                        const float w1 = wp1[kd * 9 + tap];
                        #pragma unroll
                        for (int t = 0; t < 8; ++t) {
                            const int to1 = t + 1 - kd;
                            if (to1 >= 0 && to1 < 8)
                                acc[0][to1] = fmaf(w0, vv[t], acc[0][to1]);
                            const int to2 = t + 2 - 2 * kd;
                            if (to2 >= 0 && to2 < 8)
                                acc[1][to2] = fmaf(w1, vv[t], acc[1][to2]);
                        }
                    }
                }
            }
        }
        if (cl < 7) {
            const float scn = scale[c + 1], shn = shift[c + 1];
            float* bufn = &tile[(cl + 1) & 1][0];
            #pragma unroll
            for (int k = 0; k < 2; ++k)
                if (pvld[k]) {
                    float v[8];
                    #pragma unroll
                    for (int t = 0; t < 8; ++t)
                        v[t] = fmaxf(fmaf(xn[k][t] * pav[k][t], scn, shn), 0.f);
                    int p = tid + k * 256;
                    *(float4*)&bufn[p * 12]     = make_float4(v[0], v[1], v[2], v[3]);
                    *(float4*)&bufn[p * 12 + 4] = make_float4(v[4], v[5], v[6], v[7]);
                }
        }
        __syncthreads();
    }

    if (active) {
        const int hw = (h0 + hr) * WW + wc;
        #pragma unroll
        for (int d = 0; d < 2; ++d)
            #pragma unroll
            for (int t = 0; t < 8; ++t)
                atomicAdd(&gate_raw[(((size_t)(d * 4 + b) * 2 + g) * 8 + t) * HW + hw],
                          acc[d][t]);
    }
}

// ---------------- K4b: gate = tanh(raw + bias) ----------------------------
__global__ void k4b_tanh(const float* __restrict__ raw, const float* __restrict__ gb0,
                         const float* __restrict__ gb1, float* __restrict__ gt) {
    int i = blockIdx.x * 256 + threadIdx.x;
    if (i >= 401408) return;
    int d   = i / 200704;
    int rem = i - d * 200704;
    int g   = (rem / 25088) & 1;
    float bias = (d == 0) ? gb0[g] : gb1[g];
    gt[i] = tanhf(raw[i] + bias);
}

// ---------------- K5: fuse + shuffle + alpha-combine ----------------------
__global__ __launch_bounds__(256)
void k5_fuse(const float* __restrict__ x, const float* __restrict__ attn,
             const float* __restrict__ scale, const float* __restrict__ shift,
             const float* __restrict__ gt, const float* __restrict__ alpha,
             float* __restrict__ out) {
    const int blk  = blockIdx.x;
    const int tile = blk % 13;
    const int c    = (blk / 13) & 255;
    const int b    = blk / (13 * 256);
    const int hw   = tile * 256 + threadIdx.x;
    if (hw >= HW) return;
    const int clo  = c & 127;
    const int cs   = (c & 128) | ((clo & 1) << 6) | (clo >> 1);  // inverse shuffle
    const int g    = c >> 7;
    const int head = cs >> 6;
    const float sc = scale[cs], sh = shift[cs];
    float xr[8], G0[8], G1[8];
    #pragma unroll
    for (int t = 0; t < 8; ++t) {
        const int bti = b * 8 + t;
        float xv = x[((size_t)bti * CC + cs) * HW + hw];
        float av = attn[((size_t)bti * 4 + head) * HW + hw];
        xr[t] = fmaxf(fmaf(xv * av, sc, sh), 0.f);
        G0[t] = gt[(((size_t)(0 * 4 + b) * 2 + g) * 8 + t) * HW + hw];
        G1[t] = gt[(((size_t)(1 * 4 + b) * 2 + g) * 8 + t) * HW + hw];
    }
    const float a0 = alpha[0], a1 = alpha[1];
    #pragma unroll
    for (int t = 0; t < 8; ++t) {
        float v0, v1;
        if (g == 0) {
            v0 = xr[t] * (1.f - G0[t]) + (t + 1 < 8 ? G0[t + 1] * xr[t + 1] : 0.f);
            v1 = xr[t] * (1.f - G1[t]) + (t + 2 < 8 ? G1[t + 2] * xr[t + 2] : 0.f);
        } else {
            v0 = xr[t] * (1.f - G0[t]) + (t - 1 >= 0 ? G0[t - 1] * xr[t - 1] : 0.f);
            v1 = xr[t] * (1.f - G1[t]) + (t - 2 >= 0 ? G1[t - 2] * xr[t - 2] : 0.f);
        }
        out[((size_t)(b * 8 + t) * CC + c) * HW + hw] = fmaf(a0, v0, a1 * v1);
    }
}

extern "C" void kernel_launch(void* const* d_in, const int* in_sizes, int n_in,
                              void* d_out, int out_size, void* d_ws, size_t ws_size,
                              hipStream_t stream) {
    const float* x     = (const float*)d_in[0];
    const float* aw    = (const float*)d_in[1];
    const float* ab    = (const float*)d_in[2];
    const float* gamma = (const float*)d_in[3];
    const float* beta  = (const float*)d_in[4];
    const float* gw0   = (const float*)d_in[5];
    const float* gb0   = (const float*)d_in[6];
    const float* gw1   = (const float*)d_in[7];
    const float* gb1   = (const float*)d_in[8];
    const float* alpha = (const float*)d_in[9];
    float* out = (float*)d_out;
    float* ws  = (float*)d_ws;

    // ws layout (floats):
    //   [gate_raw 401408 | attn_raw/gate_t 401408 | bn_sum 256 | bn_sumsq 256 |
    //    attn 401408 | scale 256 | shift 256]
    float* gate_raw = ws;
    float* attn_raw = ws + 401408;
    float* gate_t   = attn_raw;             // alias (timeline-disjoint)
    float* bn_sum   = ws + 802816;
    float* bn_sumsq = ws + 803072;
    float* attn     = ws + 803328;
    float* scale    = ws + 1204736;
    float* shift    = ws + 1204992;

    // zero all atomic-accumulated regions in one memset (contiguous prefix)
    hipMemsetAsync(ws, 0, (size_t)(401408 + 401408 + 512) * sizeof(float), stream);

    k1_attn <<<dim3(1792),  dim3(256), 0, stream>>>(x, aw, attn_raw);
    k1b_act <<<dim3(1568),  dim3(256), 0, stream>>>(attn_raw, ab, attn);
    k2_stats<<<dim3(8192),  dim3(256), 0, stream>>>(x, attn, bn_sum, bn_sumsq);
    k3_final<<<dim3(1),     dim3(256), 0, stream>>>(bn_sum, bn_sumsq, gamma, beta, scale, shift);
    k4_gate <<<dim3(1792),  dim3(256), 0, stream>>>(x, attn, scale, shift, gw0, gw1, gate_raw);
    k4b_tanh<<<dim3(1568),  dim3(256), 0, stream>>>(gate_raw, gb0, gb1, gate_t);
    k5_fuse <<<dim3(13312), dim3(256), 0, stream>>>(x, attn, scale, shift, gate_t, alpha, out);
}